// Round 10
// baseline (135.591 us; speedup 1.0000x reference)
//
#include <hip/hip_runtime.h>
#include <hip/hip_bf16.h>
#include <math.h>

#define N_NODES 8192
#define DEG 32
#define EMBED 256
#define NHEAD 8
#define HDIM 32

typedef __attribute__((ext_vector_type(8))) short bf16x8;
typedef __attribute__((ext_vector_type(8))) unsigned short ushort8;
typedef __attribute__((ext_vector_type(4))) float f32x4;

__device__ __forceinline__ unsigned short f2bf(float x) {
    union { float f; unsigned int u; } c; c.f = x;
    unsigned int r = (c.u + 0x7FFFu + ((c.u >> 16) & 1u)) >> 16;
    return (unsigned short)r;
}
__device__ __forceinline__ float bf2f(unsigned short u) {
    union { unsigned int u; float f; } c; c.u = ((unsigned int)u) << 16;
    return c.f;
}

// Merged conversion (each element converted exactly ONCE):
// blocks 0..2047 feats->Xb; 2048..2303 Wq/Wk/Wv/Wo -> Wqkvb/Wob; 2304 biases.
__global__ __launch_bounds__(256) void convert_all(
        const float* __restrict__ feats,
        const float* __restrict__ Wq, const float* __restrict__ Wk,
        const float* __restrict__ Wv, const float* __restrict__ Wo,
        const float* __restrict__ bq, const float* __restrict__ bk,
        const float* __restrict__ bv,
        unsigned short* __restrict__ Xb,
        unsigned short* __restrict__ Wqkvb, unsigned short* __restrict__ Wob,
        float* __restrict__ bias768) {
    const int b = blockIdx.x;
    if (b < 2048) {
        const int i = (b * 256 + threadIdx.x) * 4;
        const float4 v = *reinterpret_cast<const float4*>(&feats[i]);
        ushort4 r;
        r.x = f2bf(v.x); r.y = f2bf(v.y); r.z = f2bf(v.z); r.w = f2bf(v.w);
        *reinterpret_cast<ushort4*>(&Xb[i]) = r;
    } else if (b < 2304) {
        const int bb  = b - 2048;
        const int seg = bb >> 6;           // 0..3
        const int i = (bb & 63) * 1024 + threadIdx.x * 4;
        const float* src = (seg == 0) ? Wq : (seg == 1) ? Wk : (seg == 2) ? Wv : Wo;
        const float4 v = *reinterpret_cast<const float4*>(&src[i]);
        ushort4 r;
        r.x = f2bf(v.x); r.y = f2bf(v.y); r.z = f2bf(v.z); r.w = f2bf(v.w);
        if (seg < 3) *reinterpret_cast<ushort4*>(&Wqkvb[seg * 65536 + i]) = r;
        else         *reinterpret_cast<ushort4*>(&Wob[i]) = r;
    } else {
        const int i = threadIdx.x;
        bias768[i]       = bq[i];
        bias768[256 + i] = bk[i];
        bias768[512 + i] = bv[i];
    }
}

// C[M][N] = X @ W^T + bias, bf16 MFMA 16x16x32. BM=BN=128, BK=64.
// 4 waves (2x2), each owns a 64x64 quadrant = 4x4 frags of 16x16 (acc 64 VGPR).
// Per K-step/wave: 32 MFMA : 16 ds_read_b128 : 8 staging loads : 2 barriers.
// LDS [128][72]: 144 B rows (16B-aligned), 4-bank drift/row -> 2-way (free).
// K accumulation order identical to the proven 64-tile version (sequential
// 32-chunks) -> absmax invariant 0.0078125.
// IS_QKV=1: N=768, W=Wqkvb; cols<256 -> Qf f32, cols>=256 -> KVb bf16 [.][512].
// IS_QKV=0: N=256, W=Wob; out f32.
template <int IS_QKV>
__global__ __launch_bounds__(256) void gemm128(const unsigned short* __restrict__ X,
                                               const unsigned short* __restrict__ W,
                                               const float* __restrict__ bias,
                                               float* __restrict__ outF,
                                               unsigned short* __restrict__ outKV) {
    __shared__ unsigned short Xs[128][72];
    __shared__ unsigned short Ws[128][72];
    const int t    = threadIdx.x;
    const int bm   = blockIdx.y * 128;
    const int bn   = blockIdx.x * 128;
    const int lane = t & 63;
    const int wv   = t >> 6;
    const int wr   = (wv >> 1) * 64;   // wave row quadrant
    const int wc   = (wv & 1) * 64;    // wave col quadrant
    const int fr   = lane & 15;        // fragment row/col
    const int ksel = lane >> 4;        // 0..3 k-group

    f32x4 acc[4][4] = {};

    for (int k0 = 0; k0 < 256; k0 += 64) {
        // stage 128x64 tiles of X and W (uint4 = 8 bf16 per load)
#pragma unroll
        for (int i = 0; i < 4; ++i) {
            const int c    = i * 256 + t;   // 0..1023
            const int row  = c >> 3;        // 0..127
            const int col8 = (c & 7) * 8;   // 0..56
            *reinterpret_cast<uint4*>(&Xs[row][col8]) =
                *reinterpret_cast<const uint4*>(&X[(bm + row) * 256 + k0 + col8]);
            *reinterpret_cast<uint4*>(&Ws[row][col8]) =
                *reinterpret_cast<const uint4*>(&W[(bn + row) * 256 + k0 + col8]);
        }
        __syncthreads();
#pragma unroll
        for (int kh = 0; kh < 2; ++kh) {
            bf16x8 af[4], bg[4];
#pragma unroll
            for (int mf = 0; mf < 4; ++mf)
                af[mf] = *reinterpret_cast<const bf16x8*>(
                    &Xs[wr + mf * 16 + fr][kh * 32 + ksel * 8]);
#pragma unroll
            for (int nf = 0; nf < 4; ++nf)
                bg[nf] = *reinterpret_cast<const bf16x8*>(
                    &Ws[wc + nf * 16 + fr][kh * 32 + ksel * 8]);
#pragma unroll
            for (int mf = 0; mf < 4; ++mf)
#pragma unroll
                for (int nf = 0; nf < 4; ++nf)
                    acc[mf][nf] = __builtin_amdgcn_mfma_f32_16x16x32_bf16(
                        af[mf], bg[nf], acc[mf][nf], 0, 0, 0);
        }
        __syncthreads();
    }

    // C/D frag: col = lane&15, row = (lane>>4)*4 + reg  [verified m89/m91]
#pragma unroll
    for (int mf = 0; mf < 4; ++mf)
#pragma unroll
        for (int nf = 0; nf < 4; ++nf)
#pragma unroll
            for (int reg = 0; reg < 4; ++reg) {
                const int row = bm + wr + mf * 16 + ksel * 4 + reg;
                const int col = bn + wc + nf * 16 + fr;
                const float v = acc[mf][nf][reg] + bias[col];
                if (IS_QKV) {
                    if (col < 256) outF[row * 256 + col] = v;
                    else           outKV[row * 512 + (col - 256)] = f2bf(v);
                } else {
                    outF[row * 256 + col] = v;
                }
            }
}

// One block per dst node; 256 threads. (proven <45us, gather-BW-bound)
//  QK: thread (h,j) computes the full 32-dim dot in-thread (one 64B line).
//  Softmax: one 5-shfl butterfly within 32-lane half-waves.
//  PV: thread (h,d): 32 coalesced gathers (512B row per jj).
__global__ __launch_bounds__(256) void edge_attn(const float* __restrict__ Qf,
                                                 const unsigned short* __restrict__ KVb,
                                                 const int* __restrict__ edge_index,
                                                 unsigned short* __restrict__ attb) {
    const int n = blockIdx.x;
    const int t = threadIdx.x;
    const int h = t >> 5;
    const int j = t & 31;
    __shared__ int   s_src[DEG];
    __shared__ float Qs[EMBED];
    __shared__ float wls[NHEAD][DEG];

    if (t < DEG) s_src[t] = edge_index[(n * DEG + t) * 2];
    Qs[t] = Qf[n * EMBED + t];
    __syncthreads();

    const unsigned short* kp = &KVb[(size_t)s_src[j] * 512 + h * HDIM];
    float s = 0.f;
#pragma unroll
    for (int c = 0; c < 4; ++c) {
        const ushort8 kv = *reinterpret_cast<const ushort8*>(&kp[c * 8]);
        const float4 q0 = *reinterpret_cast<const float4*>(&Qs[h * HDIM + c * 8]);
        const float4 q1 = *reinterpret_cast<const float4*>(&Qs[h * HDIM + c * 8 + 4]);
        s = fmaf(bf2f(kv[0]), q0.x, s);
        s = fmaf(bf2f(kv[1]), q0.y, s);
        s = fmaf(bf2f(kv[2]), q0.z, s);
        s = fmaf(bf2f(kv[3]), q0.w, s);
        s = fmaf(bf2f(kv[4]), q1.x, s);
        s = fmaf(bf2f(kv[5]), q1.y, s);
        s = fmaf(bf2f(kv[6]), q1.z, s);
        s = fmaf(bf2f(kv[7]), q1.w, s);
    }
    s *= 0.17677669529663687f;  // 1/sqrt(32)

    float m = s;
    m = fmaxf(m, __shfl_xor(m, 1));
    m = fmaxf(m, __shfl_xor(m, 2));
    m = fmaxf(m, __shfl_xor(m, 4));
    m = fmaxf(m, __shfl_xor(m, 8));
    m = fmaxf(m, __shfl_xor(m, 16));
    const float p = __expf(s - m);
    float den = p;
    den += __shfl_xor(den, 1);
    den += __shfl_xor(den, 2);
    den += __shfl_xor(den, 4);
    den += __shfl_xor(den, 8);
    den += __shfl_xor(den, 16);
    wls[h][j] = p / den;
    __syncthreads();

    float o = 0.f;
#pragma unroll
    for (int jj = 0; jj < DEG; ++jj) {
        o = fmaf(wls[h][jj],
                 bf2f(KVb[(size_t)s_src[jj] * 512 + 256 + h * HDIM + j]), o);
    }
    attb[n * EMBED + t] = f2bf(o);
}

extern "C" void kernel_launch(void* const* d_in, const int* in_sizes, int n_in,
                              void* d_out, int out_size, void* d_ws, size_t ws_size,
                              hipStream_t stream) {
    const float* feats      = (const float*)d_in[0];
    const int*   edge_index = (const int*)d_in[1];
    const float* Wq = (const float*)d_in[3];
    const float* bq = (const float*)d_in[4];
    const float* Wk = (const float*)d_in[5];
    const float* bk = (const float*)d_in[6];
    const float* Wv = (const float*)d_in[7];
    const float* bv = (const float*)d_in[8];
    const float* Wo = (const float*)d_in[9];
    const float* bo = (const float*)d_in[10];
    float* out = (float*)d_out;

    // workspace layout (16B-aligned)
    unsigned short* Xb      = (unsigned short*)d_ws;                // 4 MB
    unsigned short* Wqkvb   = Xb + (size_t)8192 * 256;              // 384 KB
    unsigned short* Wob     = Wqkvb + 768 * 256;                    // 128 KB
    float*          bias768 = (float*)(Wob + 256 * 256);            // 3 KB (+pad)
    float*          Qf      = (float*)((char*)bias768 + 4096);      // 8 MB
    unsigned short* KVb     = (unsigned short*)(Qf + (size_t)8192 * 256);  // 8 MB
    unsigned short* attb    = KVb + (size_t)8192 * 512;             // 4 MB

    convert_all<<<2305, 256, 0, stream>>>(feats, Wq, Wk, Wv, Wo, bq, bk, bv,
                                          Xb, Wqkvb, Wob, bias768);
    gemm128<1><<<dim3(6, 64), 256, 0, stream>>>(Xb, Wqkvb, bias768, Qf, KVb);
    edge_attn<<<N_NODES, 256, 0, stream>>>(Qf, KVb, edge_index, attb);
    gemm128<0><<<dim3(2, 64), 256, 0, stream>>>(attb, Wob, bo, out, nullptr);
}

// Round 13
// 128.268 us; speedup vs baseline: 1.0571x; 1.0571x over previous
//
#include <hip/hip_runtime.h>
#include <hip/hip_bf16.h>
#include <math.h>

#define N_NODES 8192
#define DEG 32
#define EMBED 256
#define NHEAD 8
#define HDIM 32

typedef __attribute__((ext_vector_type(8))) short bf16x8;
typedef __attribute__((ext_vector_type(8))) unsigned short ushort8;
typedef __attribute__((ext_vector_type(4))) float f32x4;

__device__ __forceinline__ unsigned short f2bf(float x) {
    union { float f; unsigned int u; } c; c.f = x;
    unsigned int r = (c.u + 0x7FFFu + ((c.u >> 16) & 1u)) >> 16;
    return (unsigned short)r;
}
__device__ __forceinline__ float bf2f(unsigned short u) {
    union { unsigned int u; float f; } c; c.u = ((unsigned int)u) << 16;
    return c.f;
}

// Merged conversion (each element converted exactly ONCE):
// blocks 0..2047 feats->Xb; 2048..2303 Wq/Wk/Wv/Wo -> Wqkvb/Wob; 2304 biases.
__global__ __launch_bounds__(256) void convert_all(
        const float* __restrict__ feats,
        const float* __restrict__ Wq, const float* __restrict__ Wk,
        const float* __restrict__ Wv, const float* __restrict__ Wo,
        const float* __restrict__ bq, const float* __restrict__ bk,
        const float* __restrict__ bv,
        unsigned short* __restrict__ Xb,
        unsigned short* __restrict__ Wqkvb, unsigned short* __restrict__ Wob,
        float* __restrict__ bias768) {
    const int b = blockIdx.x;
    if (b < 2048) {
        const int i = (b * 256 + threadIdx.x) * 4;
        const float4 v = *reinterpret_cast<const float4*>(&feats[i]);
        ushort4 r;
        r.x = f2bf(v.x); r.y = f2bf(v.y); r.z = f2bf(v.z); r.w = f2bf(v.w);
        *reinterpret_cast<ushort4*>(&Xb[i]) = r;
    } else if (b < 2304) {
        const int bb  = b - 2048;
        const int seg = bb >> 6;           // 0..3
        const int i = (bb & 63) * 1024 + threadIdx.x * 4;
        const float* src = (seg == 0) ? Wq : (seg == 1) ? Wk : (seg == 2) ? Wv : Wo;
        const float4 v = *reinterpret_cast<const float4*>(&src[i]);
        ushort4 r;
        r.x = f2bf(v.x); r.y = f2bf(v.y); r.z = f2bf(v.z); r.w = f2bf(v.w);
        if (seg < 3) *reinterpret_cast<ushort4*>(&Wqkvb[seg * 65536 + i]) = r;
        else         *reinterpret_cast<ushort4*>(&Wob[i]) = r;
    } else {
        const int i = threadIdx.x;
        bias768[i]       = bq[i];
        bias768[256 + i] = bk[i];
        bias768[512 + i] = bv[i];
    }
}

// QKV GEMM: C[8192][768] = Xb @ Wqkvb^T + bias. BM=BN=128, BK=128.
// 4 waves (2x2), each owns 64x64 (4x4 frags). Per K-iter/wave: 64 MFMA,
// 32 ds_read_b128, 2 barriers (BK=128 quarters the barrier count vs BK=32-
// equivalent; barrier drain was the r6-r10 regression).
// LDS [128][136]: 272 B rows (16B-aligned); 4-bank drift/row -> 2-way (free).
// cols<256 -> Qf f32; cols>=256 -> KVb bf16 [8192][512] (K|V halves).
__global__ __launch_bounds__(256) void gemm_qkv(const unsigned short* __restrict__ X,
                                                const unsigned short* __restrict__ W,
                                                const float* __restrict__ bias,
                                                float* __restrict__ Qf,
                                                unsigned short* __restrict__ KVb) {
    __shared__ unsigned short Xs[128][136];
    __shared__ unsigned short Ws[128][136];
    const int t    = threadIdx.x;
    const int bm   = blockIdx.y * 128;
    const int bn   = blockIdx.x * 128;
    const int lane = t & 63;
    const int wv   = t >> 6;
    const int wr   = (wv >> 1) * 64;
    const int wc   = (wv & 1) * 64;
    const int fr   = lane & 15;
    const int ksel = lane >> 4;

    f32x4 acc[4][4] = {};

    for (int k0 = 0; k0 < 256; k0 += 128) {
        // stage 128x128 tiles of X and W (2048 uint4 slots each; 8/thread)
#pragma unroll
        for (int i = 0; i < 8; ++i) {
            const int id  = i * 256 + t;    // 0..2047
            const int row = id >> 4;        // 0..127
            const int c8  = (id & 15) * 8;  // 0..120
            *reinterpret_cast<uint4*>(&Xs[row][c8]) =
                *reinterpret_cast<const uint4*>(&X[(bm + row) * 256 + k0 + c8]);
            *reinterpret_cast<uint4*>(&Ws[row][c8]) =
                *reinterpret_cast<const uint4*>(&W[(bn + row) * 256 + k0 + c8]);
        }
        __syncthreads();
#pragma unroll
        for (int kf = 0; kf < 4; ++kf) {
            const int ck = kf * 32 + ksel * 8;
            bf16x8 af[4], bg[4];
#pragma unroll
            for (int mf = 0; mf < 4; ++mf)
                af[mf] = *reinterpret_cast<const bf16x8*>(&Xs[wr + mf * 16 + fr][ck]);
#pragma unroll
            for (int nf = 0; nf < 4; ++nf)
                bg[nf] = *reinterpret_cast<const bf16x8*>(&Ws[wc + nf * 16 + fr][ck]);
#pragma unroll
            for (int mf = 0; mf < 4; ++mf)
#pragma unroll
                for (int nf = 0; nf < 4; ++nf)
                    acc[mf][nf] = __builtin_amdgcn_mfma_f32_16x16x32_bf16(
                        af[mf], bg[nf], acc[mf][nf], 0, 0, 0);
        }
        __syncthreads();
    }

    // C/D frag: col = lane&15, row = (lane>>4)*4 + reg  [verified m89/m91]
#pragma unroll
    for (int mf = 0; mf < 4; ++mf)
#pragma unroll
        for (int nf = 0; nf < 4; ++nf)
#pragma unroll
            for (int reg = 0; reg < 4; ++reg) {
                const int row = bm + wr + mf * 16 + ksel * 4 + reg;
                const int col = bn + wc + nf * 16 + fr;
                const float v = acc[mf][nf][reg] + bias[col];
                if (col < 256) Qf[row * 256 + col] = v;
                else           KVb[row * 512 + (col - 256)] = f2bf(v);
            }
}

// O-proj GEMM (r3-proven shape): C[8192][256] = attb @ Wob^T + bo.
// BM=BN=64, BK=128, 4 waves each a 32x32 quadrant (2x2 frags).
__global__ __launch_bounds__(256) void gemm_o(const unsigned short* __restrict__ X,
                                              const unsigned short* __restrict__ W,
                                              const float* __restrict__ bias,
                                              float* __restrict__ outF) {
    __shared__ unsigned short Xs[64][136];
    __shared__ unsigned short Ws[64][136];
    const int t    = threadIdx.x;
    const int bm   = blockIdx.y * 64;
    const int bn   = blockIdx.x * 64;
    const int lane = t & 63;
    const int wv   = t >> 6;
    const int wm   = (wv >> 1) * 32;
    const int wn   = (wv & 1) * 32;
    const int fr   = lane & 15;
    const int ksel = lane >> 4;

    f32x4 acc[2][2] = {};

    for (int k0 = 0; k0 < 256; k0 += 128) {
#pragma unroll
        for (int i = 0; i < 4; ++i) {
            const int id  = i * 256 + t;    // 0..1023
            const int row = id >> 4;        // 0..63
            const int c8  = (id & 15) * 8;  // 0..120
            *reinterpret_cast<uint4*>(&Xs[row][c8]) =
                *reinterpret_cast<const uint4*>(&X[(bm + row) * 256 + k0 + c8]);
            *reinterpret_cast<uint4*>(&Ws[row][c8]) =
                *reinterpret_cast<const uint4*>(&W[(bn + row) * 256 + k0 + c8]);
        }
        __syncthreads();
#pragma unroll
        for (int kf = 0; kf < 4; ++kf) {
            const int ck = kf * 32 + ksel * 8;
            bf16x8 a0 = *reinterpret_cast<const bf16x8*>(&Xs[wm + fr][ck]);
            bf16x8 a1 = *reinterpret_cast<const bf16x8*>(&Xs[wm + 16 + fr][ck]);
            bf16x8 b0 = *reinterpret_cast<const bf16x8*>(&Ws[wn + fr][ck]);
            bf16x8 b1 = *reinterpret_cast<const bf16x8*>(&Ws[wn + 16 + fr][ck]);
            acc[0][0] = __builtin_amdgcn_mfma_f32_16x16x32_bf16(a0, b0, acc[0][0], 0, 0, 0);
            acc[0][1] = __builtin_amdgcn_mfma_f32_16x16x32_bf16(a0, b1, acc[0][1], 0, 0, 0);
            acc[1][0] = __builtin_amdgcn_mfma_f32_16x16x32_bf16(a1, b0, acc[1][0], 0, 0, 0);
            acc[1][1] = __builtin_amdgcn_mfma_f32_16x16x32_bf16(a1, b1, acc[1][1], 0, 0, 0);
        }
        __syncthreads();
    }

#pragma unroll
    for (int mf = 0; mf < 2; ++mf)
#pragma unroll
        for (int nf = 0; nf < 2; ++nf)
#pragma unroll
            for (int reg = 0; reg < 4; ++reg) {
                const int row = bm + wm + mf * 16 + ksel * 4 + reg;
                const int col = bn + wn + nf * 16 + fr;
                outF[row * 256 + col] = acc[mf][nf][reg] + bias[col];
            }
}

// One block per dst node; 256 threads. (measured ~44us, gather-bound)
//  QK: thread (h,j) computes the full 32-dim dot in-thread (one 64B line).
//  Softmax: one 5-shfl butterfly within 32-lane half-waves.
//  PV: thread (h,d): 32 coalesced gathers (512B row per jj).
__global__ __launch_bounds__(256) void edge_attn(const float* __restrict__ Qf,
                                                 const unsigned short* __restrict__ KVb,
                                                 const int* __restrict__ edge_index,
                                                 unsigned short* __restrict__ attb) {
    const int n = blockIdx.x;
    const int t = threadIdx.x;
    const int h = t >> 5;
    const int j = t & 31;
    __shared__ int   s_src[DEG];
    __shared__ float Qs[EMBED];
    __shared__ float wls[NHEAD][DEG];

    if (t < DEG) s_src[t] = edge_index[(n * DEG + t) * 2];
    Qs[t] = Qf[n * EMBED + t];
    __syncthreads();

    const unsigned short* kp = &KVb[(size_t)s_src[j] * 512 + h * HDIM];
    float s = 0.f;
#pragma unroll
    for (int c = 0; c < 4; ++c) {
        const ushort8 kv = *reinterpret_cast<const ushort8*>(&kp[c * 8]);
        const float4 q0 = *reinterpret_cast<const float4*>(&Qs[h * HDIM + c * 8]);
        const float4 q1 = *reinterpret_cast<const float4*>(&Qs[h * HDIM + c * 8 + 4]);
        s = fmaf(bf2f(kv[0]), q0.x, s);
        s = fmaf(bf2f(kv[1]), q0.y, s);
        s = fmaf(bf2f(kv[2]), q0.z, s);
        s = fmaf(bf2f(kv[3]), q0.w, s);
        s = fmaf(bf2f(kv[4]), q1.x, s);
        s = fmaf(bf2f(kv[5]), q1.y, s);
        s = fmaf(bf2f(kv[6]), q1.z, s);
        s = fmaf(bf2f(kv[7]), q1.w, s);
    }
    s *= 0.17677669529663687f;  // 1/sqrt(32)

    float m = s;
    m = fmaxf(m, __shfl_xor(m, 1));
    m = fmaxf(m, __shfl_xor(m, 2));
    m = fmaxf(m, __shfl_xor(m, 4));
    m = fmaxf(m, __shfl_xor(m, 8));
    m = fmaxf(m, __shfl_xor(m, 16));
    const float p = __expf(s - m);
    float den = p;
    den += __shfl_xor(den, 1);
    den += __shfl_xor(den, 2);
    den += __shfl_xor(den, 4);
    den += __shfl_xor(den, 8);
    den += __shfl_xor(den, 16);
    wls[h][j] = p / den;
    __syncthreads();

    float o = 0.f;
#pragma unroll
    for (int jj = 0; jj < DEG; ++jj) {
        o = fmaf(wls[h][jj],
                 bf2f(KVb[(size_t)s_src[jj] * 512 + 256 + h * HDIM + j]), o);
    }
    attb[n * EMBED + t] = f2bf(o);
}

extern "C" void kernel_launch(void* const* d_in, const int* in_sizes, int n_in,
                              void* d_out, int out_size, void* d_ws, size_t ws_size,
                              hipStream_t stream) {
    const float* feats      = (const float*)d_in[0];
    const int*   edge_index = (const int*)d_in[1];
    const float* Wq = (const float*)d_in[3];
    const float* bq = (const float*)d_in[4];
    const float* Wk = (const float*)d_in[5];
    const float* bk = (const float*)d_in[6];
    const float* Wv = (const float*)d_in[7];
    const float* bv = (const float*)d_in[8];
    const float* Wo = (const float*)d_in[9];
    const float* bo = (const float*)d_in[10];
    float* out = (float*)d_out;

    // workspace layout (16B-aligned)
    unsigned short* Xb      = (unsigned short*)d_ws;                // 4 MB
    unsigned short* Wqkvb   = Xb + (size_t)8192 * 256;              // 384 KB
    unsigned short* Wob     = Wqkvb + 768 * 256;                    // 128 KB
    float*          bias768 = (float*)(Wob + 256 * 256);            // 3 KB (+pad)
    float*          Qf      = (float*)((char*)bias768 + 4096);      // 8 MB
    unsigned short* KVb     = (unsigned short*)(Qf + (size_t)8192 * 256);  // 8 MB
    unsigned short* attb    = KVb + (size_t)8192 * 512;             // 4 MB

    convert_all<<<2305, 256, 0, stream>>>(feats, Wq, Wk, Wv, Wo, bq, bk, bv,
                                          Xb, Wqkvb, Wob, bias768);
    gemm_qkv<<<dim3(6, 64), 256, 0, stream>>>(Xb, Wqkvb, bias768, Qf, KVb);
    edge_attn<<<N_NODES, 256, 0, stream>>>(Qf, KVb, edge_index, attb);
    gemm_o<<<dim3(4, 128), 256, 0, stream>>>(attb, Wob, bo, out);
}